// Round 11
// baseline (151.776 us; speedup 1.0000x reference)
//
#include <hip/hip_runtime.h>
#include <hip/hip_bf16.h>

namespace {
constexpr int kB    = 8192;
constexpr int kNB   = 64;
constexpr int kF    = 256;
constexpr int kK    = 8;
constexpr int kKS   = 5;
constexpr int kH    = 256;
constexpr int kOUT  = 128;
constexpr int kXR   = 9;   // x rows (1 node + 8 topk)
constexpr int kTO   = 5;   // conv1 output positions
constexpr int kBM   = 16;  // batch rows per block

constexpr int XPAD = 258;   // A-row stride 9*258 el = 1161 dw ≡ 9 (odd) mod 32 -> conflict-free
constexpr int HPAD = 1290;  // h row stride 645 dw ≡ 5 (odd) mod 32 -> conflict-free

// workspace layout (bytes)
constexpr size_t W1T_OFF  = 0;                                    // bf16 [5][256(hc)][256(f)]
constexpr size_t W2T_OFF  = W1T_OFF + (size_t)kKS * kH * kF * 2;  // bf16 [128(o)][1280(k)]
constexpr size_t GATE_OFF = W2T_OFF + (size_t)kOUT * kKS * kH * 2;

typedef __attribute__((ext_vector_type(8))) short short8; // 8 bf16 (A/B frag)
typedef __attribute__((ext_vector_type(4))) float f32x4;  // C/D frag / gather vector
}

using bf16 = __hip_bfloat16;

__device__ __forceinline__ unsigned short f2bf(float f) {
  bf16 h = __float2bfloat16(f);
  return *reinterpret_cast<unsigned short*>(&h);
}

// ---- sc0 (L1-bypass) pipelined gather primitives (R8, benched best) ----
#define STR_(x) #x
#define WAITV(n) do { asm volatile("s_waitcnt vmcnt(" STR_(n) ")" ::: "memory"); \
                      __builtin_amdgcn_sched_barrier(0); } while (0)

#define GLOAD(dst, idx) do { \
  const int rr_ = __builtin_amdgcn_readlane(myn, (idx)); \
  const unsigned long long ad_ = fb + ((unsigned long long)(unsigned)rr_ << 10); \
  asm volatile("global_load_dwordx4 %0, %1, off sc0" : "=v"(dst) : "v"(ad_)); \
} while (0)

#define ISSUE6(B, g) do { GLOAD(B[0], (g)*6+0); GLOAD(B[1], (g)*6+1); GLOAD(B[2], (g)*6+2); \
                          GLOAD(B[3], (g)*6+3); GLOAD(B[4], (g)*6+4); GLOAD(B[5], (g)*6+5); } while (0)
#define ISSUE4(B, g) do { GLOAD(B[0], (g)*6+0); GLOAD(B[1], (g)*6+1); GLOAD(B[2], (g)*6+2); \
                          GLOAD(B[3], (g)*6+3); } while (0)
#define PROC6(B) do { ins4(B[0]); ins4(B[1]); ins4(B[2]); ins4(B[3]); ins4(B[4]); ins4(B[5]); } while (0)
#define PROC4(B) do { ins4(B[0]); ins4(B[1]); ins4(B[2]); ins4(B[3]); } while (0)

// ---------------- kernel 1: weight convert/transpose to bf16 ----------------
__global__ void convert_weights(const float* __restrict__ W1,
                                const float* __restrict__ W2,
                                bf16* __restrict__ w1t, bf16* __restrict__ w2t)
{
  const int i = blockIdx.x * 256 + threadIdx.x;
  const int stride = gridDim.x * 256;
  for (int idx = i; idx < kKS * kH * kF; idx += stride) {
    const int f  = idx & 255;
    const int hc = (idx >> 8) & 255;
    const int dt = idx >> 16;
    w1t[idx] = __float2bfloat16(W1[(dt * kF + f) * kH + hc]);
  }
  for (int idx = i; idx < kOUT * kKS * kH; idx += stride) {
    const int k = idx % (kKS * kH);
    const int o = idx / (kKS * kH);
    w2t[idx] = __float2bfloat16(W2[k * kOUT + o]);
  }
}

// ---------------- kernel 2: fused gather+topk+conv1+conv2, staggered ----------------
// R8 structure (512 threads, kBM=16, 2 blocks/CU, sc0 12-deep gather pipeline)
// + a pure-timing stagger gate: blocks <256 gather immediately and signal;
// blocks >=256 bounded-spin until all early gathers finish (or timeout), so
// the early half's conv overlaps the late half's gather. Gate never affects
// data -> bit-identical output.
__global__ __launch_bounds__(512, 4)
void fused_all(const int* __restrict__ node_ids,
               const int* __restrict__ neighbors,
               const float* __restrict__ feat,
               const bf16* __restrict__ w1t, const bf16* __restrict__ w2t,
               const float* __restrict__ b1, const float* __restrict__ b2,
               float* __restrict__ out, int* __restrict__ gate)
{
  __shared__ bf16 smem[kBM * kXR * XPAD];  // 74304 B -> 2 blocks/CU
  bf16* xs = smem;
  bf16* hs = smem;

  const int tid  = threadIdx.x;
  const int wave = tid >> 6;       // 0..7
  const int lane = tid & 63;
  const int r = lane & 15;
  const int q = lane >> 4;
  const int bbase = blockIdx.x * kBM;
  const int f4 = lane << 2;
  const bool early = (blockIdx.x < 256);

  // ---- stagger gate: late half waits for early half's gathers (bounded) ----
  if (!early) {
    if (tid == 0) {
      for (int t = 0; t < 128; ++t) {   // cap ~215 us -> deadlock-free
        if (__hip_atomic_load(gate, __ATOMIC_RELAXED, __HIP_MEMORY_SCOPE_AGENT) >= 256)
          break;
        __builtin_amdgcn_s_sleep(63);
      }
    }
    __syncthreads();
  }

  // ================= gather + per-channel top-8 -> LDS (bf16) =================
  int   myn2[2];
  f32x4 node2[2];
#pragma unroll
  for (int bb = 0; bb < 2; ++bb) {
    const int b = bbase + wave * 2 + bb;
    myn2[bb]  = neighbors[(size_t)b * kNB + lane];
    node2[bb] = *reinterpret_cast<const f32x4*>(feat + (size_t)node_ids[b] * kF + f4);
  }

#pragma unroll
  for (int bb = 0; bb < 2; ++bb) {
    const int bl  = wave * 2 + bb;                 // local batch row 0..15
    const int myn = myn2[bb];
    const unsigned long long fb =
        (unsigned long long)(uintptr_t)feat + (unsigned)(f4 * 4);

    float tk[4][kK];
#pragma unroll
    for (int c = 0; c < 4; ++c)
#pragma unroll
      for (int k = 0; k < kK; ++k) tk[c][k] = -INFINITY;

    // sorted insert via med3 network: 8 ops/channel, 1-deep chain.
    auto ins4 = [&](const f32x4& v) {
#pragma unroll
      for (int c = 0; c < 4; ++c) {
        const float vc = v[c];
        float nt[kK];
        nt[0] = fmaxf(tk[c][0], vc);
#pragma unroll
        for (int k = 1; k < kK; ++k)
          nt[k] = __builtin_amdgcn_fmed3f(tk[c][k - 1], tk[c][k], vc);
#pragma unroll
        for (int k = 0; k < kK; ++k) tk[c][k] = nt[k];
      }
    };

    f32x4 bufA[6], bufB[6];
    // 64 rows = 10 groups of 6 + tail of 4; 12 loads in flight steady-state.
    ISSUE6(bufA, 0);
    ISSUE6(bufB, 1);
    WAITV(6); PROC6(bufA); ISSUE6(bufA, 2);
    WAITV(6); PROC6(bufB); ISSUE6(bufB, 3);
    WAITV(6); PROC6(bufA); ISSUE6(bufA, 4);
    WAITV(6); PROC6(bufB); ISSUE6(bufB, 5);
    WAITV(6); PROC6(bufA); ISSUE6(bufA, 6);
    WAITV(6); PROC6(bufB); ISSUE6(bufB, 7);
    WAITV(6); PROC6(bufA); ISSUE6(bufA, 8);
    WAITV(6); PROC6(bufB); ISSUE6(bufB, 9);
    WAITV(6); PROC6(bufA); ISSUE4(bufA, 10);   // rows 60..63
    WAITV(4); PROC6(bufB);                     // group 9
    WAITV(0); PROC4(bufA);                     // tail rows 60..63

    bf16* xb = xs + (size_t)bl * kXR * XPAD + f4;
    {
      ushort4 s = {f2bf(node2[bb][0]), f2bf(node2[bb][1]),
                   f2bf(node2[bb][2]), f2bf(node2[bb][3])};
      *reinterpret_cast<ushort4*>(xb) = s;
    }
#pragma unroll
    for (int k = 0; k < kK; ++k) {
      ushort4 s = {f2bf(tk[0][k]), f2bf(tk[1][k]), f2bf(tk[2][k]), f2bf(tk[3][k])};
      *reinterpret_cast<ushort4*>(xb + (size_t)(1 + k) * XPAD) = s;
    }
  }
  __syncthreads();

  // early blocks signal: my gather traffic is done
  if (early && tid == 0)
    __hip_atomic_fetch_add(gate, 1, __ATOMIC_RELAXED, __HIP_MEMORY_SCOPE_AGENT);

  // ===== GEMM1: h[b][t][hc] = sum_dt,f x[b][t+dt][f]*W1[dt][f][hc] + b1 =====
  const int ntb = wave * 32;
  f32x4 acc[kTO][2];
#pragma unroll
  for (int n = 0; n < 2; ++n) {
    const float bv = b1[ntb + n * 16 + r];
#pragma unroll
    for (int m = 0; m < kTO; ++m) acc[m][n] = (f32x4){bv, bv, bv, bv};
  }

  for (int kk = 0; kk < 8; ++kk) {
    short8 a[kXR];
#pragma unroll
    for (int rr = 0; rr < kXR; ++rr)
      a[rr] = *reinterpret_cast<const short8*>(&xs[(r * kXR + rr) * XPAD + kk * 32 + q * 8]);
#pragma unroll
    for (int dt = 0; dt < kKS; ++dt) {
      short8 bfr[2];
#pragma unroll
      for (int n = 0; n < 2; ++n)
        bfr[n] = *reinterpret_cast<const short8*>(
            &w1t[((size_t)(dt * kH + ntb + n * 16 + r)) * kF + kk * 32 + q * 8]);
#pragma unroll
      for (int m = 0; m < kTO; ++m)
#pragma unroll
        for (int n = 0; n < 2; ++n)
          acc[m][n] = __builtin_amdgcn_mfma_f32_16x16x32_bf16(a[m + dt], bfr[n], acc[m][n], 0, 0, 0);
    }
  }
  __syncthreads();  // all waves done reading xs; safe to overwrite with h

  // ---- write h (bf16) into LDS: hs[b][t*256 + hc]  (C/D: col=lane&15, row=q*4+j) ----
#pragma unroll
  for (int m = 0; m < kTO; ++m)
#pragma unroll
    for (int n = 0; n < 2; ++n)
#pragma unroll
      for (int j = 0; j < 4; ++j)
        hs[(q * 4 + j) * HPAD + m * kH + ntb + n * 16 + r] = __float2bfloat16(acc[m][n][j]);
  __syncthreads();

  // ===== GEMM2: out[b][o] = sum_k h[b][k]*W2T[o][k] + b2 =====
  const int ob = wave * 16;
  f32x4 acc2;
  {
    const float bv = b2[ob + r];
    acc2 = (f32x4){bv, bv, bv, bv};
  }
  for (int ks = 0; ks < 40; ++ks) {
    short8 a2 = *reinterpret_cast<const short8*>(&hs[r * HPAD + ks * 32 + q * 8]);
    short8 b2f = *reinterpret_cast<const short8*>(
        &w2t[(size_t)(ob + r) * (kKS * kH) + ks * 32 + q * 8]);
    acc2 = __builtin_amdgcn_mfma_f32_16x16x32_bf16(a2, b2f, acc2, 0, 0, 0);
  }
#pragma unroll
  for (int j = 0; j < 4; ++j)
    out[(size_t)(bbase + q * 4 + j) * kOUT + ob + r] = acc2[j];
}

extern "C" void kernel_launch(void* const* d_in, const int* in_sizes, int n_in,
                              void* d_out, int out_size, void* d_ws, size_t ws_size,
                              hipStream_t stream) {
  const int*   node_ids  = (const int*)  d_in[0];
  const int*   neighbors = (const int*)  d_in[1];
  const float* feat      = (const float*)d_in[2];
  const float* W1        = (const float*)d_in[3];
  const float* b1        = (const float*)d_in[4];
  const float* W2        = (const float*)d_in[5];
  const float* b2        = (const float*)d_in[6];
  float* out = (float*)d_out;

  char* ws = (char*)d_ws;
  bf16* w1t = (bf16*)(ws + W1T_OFF);
  bf16* w2t = (bf16*)(ws + W2T_OFF);
  int*  gate = (int*)(ws + GATE_OFF);

  hipMemsetAsync(gate, 0, sizeof(int), stream);   // re-arm gate every launch
  convert_weights<<<1024, 256, 0, stream>>>(W1, W2, w1t, w2t);
  fused_all<<<kB / kBM, 512, 0, stream>>>(node_ids, neighbors, feat,
                                          w1t, w2t, b1, b2, out, gate);
}

// Round 12
// 138.134 us; speedup vs baseline: 1.0988x; 1.0988x over previous
//
#include <hip/hip_runtime.h>
#include <hip/hip_bf16.h>

namespace {
constexpr int kB    = 8192;
constexpr int kNB   = 64;
constexpr int kF    = 256;
constexpr int kK    = 8;
constexpr int kKS   = 5;
constexpr int kH    = 256;
constexpr int kOUT  = 128;
constexpr int kXR   = 9;   // x rows (1 node + 8 topk)
constexpr int kTO   = 5;   // conv1 output positions
constexpr int kBM   = 16;  // batch rows per block

constexpr int XPAD = 258;   // A-row stride 9*258 el = 1161 dw ≡ 9 (odd) mod 32 -> conflict-free
constexpr int HPAD = 1290;  // h row stride 645 dw ≡ 5 (odd) mod 32 -> conflict-free

// workspace layout (bytes)
constexpr size_t W1T_OFF = 0;                                   // bf16 [5][256(hc)][256(f)]
constexpr size_t W2T_OFF = W1T_OFF + (size_t)kKS * kH * kF * 2; // bf16 [128(o)][1280(k)]

typedef __attribute__((ext_vector_type(8))) short short8; // 8 bf16 (A/B frag)
typedef __attribute__((ext_vector_type(4))) float f32x4;  // C/D frag / gather vector
}

using bf16 = __hip_bfloat16;

__device__ __forceinline__ unsigned short f2bf(float f) {
  bf16 h = __float2bfloat16(f);
  return *reinterpret_cast<unsigned short*>(&h);
}

// ---- sc0 (L1-bypass) pipelined gather primitives ----
// Loads are issued via inline asm (compiler does not track them), so waits
// are manual counted vmcnt + sched_barrier(0) per the rule-18 pattern.
#define STR_(x) #x
#define WAITV(n) do { asm volatile("s_waitcnt vmcnt(" STR_(n) ")" ::: "memory"); \
                      __builtin_amdgcn_sched_barrier(0); } while (0)

#define GLOAD(dst, idx) do { \
  const int rr_ = __builtin_amdgcn_readlane(myn, (idx)); \
  const unsigned long long ad_ = fb + ((unsigned long long)(unsigned)rr_ << 10); \
  asm volatile("global_load_dwordx4 %0, %1, off sc0" : "=v"(dst) : "v"(ad_)); \
} while (0)

#define ISSUE6(B, g) do { GLOAD(B[0], (g)*6+0); GLOAD(B[1], (g)*6+1); GLOAD(B[2], (g)*6+2); \
                          GLOAD(B[3], (g)*6+3); GLOAD(B[4], (g)*6+4); GLOAD(B[5], (g)*6+5); } while (0)
#define ISSUE4(B, g) do { GLOAD(B[0], (g)*6+0); GLOAD(B[1], (g)*6+1); GLOAD(B[2], (g)*6+2); \
                          GLOAD(B[3], (g)*6+3); } while (0)
#define PROC6(B) do { ins4(B[0]); ins4(B[1]); ins4(B[2]); ins4(B[3]); ins4(B[4]); ins4(B[5]); } while (0)
#define PROC4(B) do { ins4(B[0]); ins4(B[1]); ins4(B[2]); ins4(B[3]); } while (0)

// ---------------- kernel 1: weight convert/transpose to bf16 ----------------
__global__ void convert_weights(const float* __restrict__ W1,
                                const float* __restrict__ W2,
                                bf16* __restrict__ w1t, bf16* __restrict__ w2t)
{
  const int i = blockIdx.x * 256 + threadIdx.x;
  const int stride = gridDim.x * 256;
  for (int idx = i; idx < kKS * kH * kF; idx += stride) {
    const int f  = idx & 255;
    const int hc = (idx >> 8) & 255;
    const int dt = idx >> 16;
    w1t[idx] = __float2bfloat16(W1[(dt * kF + f) * kH + hc]);
  }
  for (int idx = i; idx < kOUT * kKS * kH; idx += stride) {
    const int k = idx % (kKS * kH);
    const int o = idx / (kKS * kH);
    w2t[idx] = __float2bfloat16(W2[k * kOUT + o]);
  }
}

// ---------------- kernel 2: fused gather+topk+conv1+conv2 ----------------
// 512 threads (8 waves), kBM=16 rows/block, 2 blocks/CU. Gather loads use
// sc0 (L1 bypass); pipelined 12-deep in two register groups of 6 with
// counted vmcnt waits. Best measured configuration (R8: 138.4 us).
__global__ __launch_bounds__(512, 4)
void fused_all(const int* __restrict__ node_ids,
               const int* __restrict__ neighbors,
               const float* __restrict__ feat,
               const bf16* __restrict__ w1t, const bf16* __restrict__ w2t,
               const float* __restrict__ b1, const float* __restrict__ b2,
               float* __restrict__ out)
{
  __shared__ bf16 smem[kBM * kXR * XPAD];  // 74304 B -> 2 blocks/CU
  bf16* xs = smem;
  bf16* hs = smem;

  const int tid  = threadIdx.x;
  const int wave = tid >> 6;       // 0..7
  const int lane = tid & 63;
  const int r = lane & 15;
  const int q = lane >> 4;
  const int bbase = blockIdx.x * kBM;
  const int f4 = lane << 2;

  // ================= gather + per-channel top-8 -> LDS (bf16) =================
  int   myn2[2];
  f32x4 node2[2];
#pragma unroll
  for (int bb = 0; bb < 2; ++bb) {
    const int b = bbase + wave * 2 + bb;
    myn2[bb]  = neighbors[(size_t)b * kNB + lane];
    node2[bb] = *reinterpret_cast<const f32x4*>(feat + (size_t)node_ids[b] * kF + f4);
  }

#pragma unroll
  for (int bb = 0; bb < 2; ++bb) {
    const int bl  = wave * 2 + bb;                 // local batch row 0..15
    const int myn = myn2[bb];
    const unsigned long long fb =
        (unsigned long long)(uintptr_t)feat + (unsigned)(f4 * 4);

    float tk[4][kK];
#pragma unroll
    for (int c = 0; c < 4; ++c)
#pragma unroll
      for (int k = 0; k < kK; ++k) tk[c][k] = -INFINITY;

    // sorted insert via med3 network: 8 ops/channel, 1-deep chain.
    auto ins4 = [&](const f32x4& v) {
#pragma unroll
      for (int c = 0; c < 4; ++c) {
        const float vc = v[c];
        float nt[kK];
        nt[0] = fmaxf(tk[c][0], vc);
#pragma unroll
        for (int k = 1; k < kK; ++k)
          nt[k] = __builtin_amdgcn_fmed3f(tk[c][k - 1], tk[c][k], vc);
#pragma unroll
        for (int k = 0; k < kK; ++k) tk[c][k] = nt[k];
      }
    };

    f32x4 bufA[6], bufB[6];
    // 64 rows = 10 groups of 6 + tail of 4; 12 loads in flight steady-state.
    ISSUE6(bufA, 0);
    ISSUE6(bufB, 1);
    WAITV(6); PROC6(bufA); ISSUE6(bufA, 2);
    WAITV(6); PROC6(bufB); ISSUE6(bufB, 3);
    WAITV(6); PROC6(bufA); ISSUE6(bufA, 4);
    WAITV(6); PROC6(bufB); ISSUE6(bufB, 5);
    WAITV(6); PROC6(bufA); ISSUE6(bufA, 6);
    WAITV(6); PROC6(bufB); ISSUE6(bufB, 7);
    WAITV(6); PROC6(bufA); ISSUE6(bufA, 8);
    WAITV(6); PROC6(bufB); ISSUE6(bufB, 9);
    WAITV(6); PROC6(bufA); ISSUE4(bufA, 10);   // rows 60..63
    WAITV(4); PROC6(bufB);                     // group 9
    WAITV(0); PROC4(bufA);                     // tail rows 60..63

    bf16* xb = xs + (size_t)bl * kXR * XPAD + f4;
    {
      ushort4 s = {f2bf(node2[bb][0]), f2bf(node2[bb][1]),
                   f2bf(node2[bb][2]), f2bf(node2[bb][3])};
      *reinterpret_cast<ushort4*>(xb) = s;
    }
#pragma unroll
    for (int k = 0; k < kK; ++k) {
      ushort4 s = {f2bf(tk[0][k]), f2bf(tk[1][k]), f2bf(tk[2][k]), f2bf(tk[3][k])};
      *reinterpret_cast<ushort4*>(xb + (size_t)(1 + k) * XPAD) = s;
    }
  }
  __syncthreads();

  // ===== GEMM1: h[b][t][hc] = sum_dt,f x[b][t+dt][f]*W1[dt][f][hc] + b1 =====
  const int ntb = wave * 32;
  f32x4 acc[kTO][2];
#pragma unroll
  for (int n = 0; n < 2; ++n) {
    const float bv = b1[ntb + n * 16 + r];
#pragma unroll
    for (int m = 0; m < kTO; ++m) acc[m][n] = (f32x4){bv, bv, bv, bv};
  }

  for (int kk = 0; kk < 8; ++kk) {
    short8 a[kXR];
#pragma unroll
    for (int rr = 0; rr < kXR; ++rr)
      a[rr] = *reinterpret_cast<const short8*>(&xs[(r * kXR + rr) * XPAD + kk * 32 + q * 8]);
#pragma unroll
    for (int dt = 0; dt < kKS; ++dt) {
      short8 bfr[2];
#pragma unroll
      for (int n = 0; n < 2; ++n)
        bfr[n] = *reinterpret_cast<const short8*>(
            &w1t[((size_t)(dt * kH + ntb + n * 16 + r)) * kF + kk * 32 + q * 8]);
#pragma unroll
      for (int m = 0; m < kTO; ++m)
#pragma unroll
        for (int n = 0; n < 2; ++n)
          acc[m][n] = __builtin_amdgcn_mfma_f32_16x16x32_bf16(a[m + dt], bfr[n], acc[m][n], 0, 0, 0);
    }
  }
  __syncthreads();  // all waves done reading xs; safe to overwrite with h

  // ---- write h (bf16) into LDS: hs[b][t*256 + hc]  (C/D: col=lane&15, row=q*4+j) ----
#pragma unroll
  for (int m = 0; m < kTO; ++m)
#pragma unroll
    for (int n = 0; n < 2; ++n)
#pragma unroll
      for (int j = 0; j < 4; ++j)
        hs[(q * 4 + j) * HPAD + m * kH + ntb + n * 16 + r] = __float2bfloat16(acc[m][n][j]);
  __syncthreads();

  // ===== GEMM2: out[b][o] = sum_k h[b][k]*W2T[o][k] + b2 =====
  const int ob = wave * 16;
  f32x4 acc2;
  {
    const float bv = b2[ob + r];
    acc2 = (f32x4){bv, bv, bv, bv};
  }
  for (int ks = 0; ks < 40; ++ks) {
    short8 a2 = *reinterpret_cast<const short8*>(&hs[r * HPAD + ks * 32 + q * 8]);
    short8 b2f = *reinterpret_cast<const short8*>(
        &w2t[(size_t)(ob + r) * (kKS * kH) + ks * 32 + q * 8]);
    acc2 = __builtin_amdgcn_mfma_f32_16x16x32_bf16(a2, b2f, acc2, 0, 0, 0);
  }
#pragma unroll
  for (int j = 0; j < 4; ++j)
    out[(size_t)(bbase + q * 4 + j) * kOUT + ob + r] = acc2[j];
}

extern "C" void kernel_launch(void* const* d_in, const int* in_sizes, int n_in,
                              void* d_out, int out_size, void* d_ws, size_t ws_size,
                              hipStream_t stream) {
  const int*   node_ids  = (const int*)  d_in[0];
  const int*   neighbors = (const int*)  d_in[1];
  const float* feat      = (const float*)d_in[2];
  const float* W1        = (const float*)d_in[3];
  const float* b1        = (const float*)d_in[4];
  const float* W2        = (const float*)d_in[5];
  const float* b2        = (const float*)d_in[6];
  float* out = (float*)d_out;

  char* ws = (char*)d_ws;
  bf16* w1t = (bf16*)(ws + W1T_OFF);
  bf16* w2t = (bf16*)(ws + W2T_OFF);

  convert_weights<<<1024, 256, 0, stream>>>(W1, W2, w1t, w2t);
  fused_all<<<kB / kBM, 512, 0, stream>>>(node_ids, neighbors, feat, w1t, w2t, b1, b2, out);
}